// Round 3
// baseline (2741.899 us; speedup 1.0000x reference)
//
#include <hip/hip_runtime.h>

typedef __bf16 bf16x8 __attribute__((ext_vector_type(8)));
typedef float f32x4 __attribute__((ext_vector_type(4)));
typedef unsigned int u32x4 __attribute__((ext_vector_type(4)));
typedef const __attribute__((address_space(1))) unsigned int* gas_u32p;
typedef __attribute__((address_space(3))) unsigned int* las_u32p;

#define S_LEN 256
#define BATCH 64
#define HID   1024
#define NWG   256
#define SBH   (S_LEN * BATCH * HID)   /* 16777216 */
#define BH    (BATCH * HID)           /* 65536 */

__device__ __forceinline__ float sigm(float v) { return 1.0f / (1.0f + __expf(-v)); }
__device__ __forceinline__ float tanh_fast(float v) {
  float e = __expf(-2.0f * __builtin_fabsf(v));
  float r = (1.0f - e) / (1.0f + e);
  return __builtin_copysignf(r, v);
}

__global__ void prep_kernel(const float* __restrict__ x, const float* __restrict__ h0,
                            const float* __restrict__ Wf, const float* __restrict__ Wi,
                            const float* __restrict__ Wg, const float* __restrict__ Wo,
                            __bf16* __restrict__ x_bf, __bf16* __restrict__ w_x,
                            __bf16* __restrict__ w_h, __bf16* __restrict__ h_buf,
                            int* __restrict__ counters) {
  size_t tid = (size_t)blockIdx.x * blockDim.x + threadIdx.x;
  size_t stride = (size_t)gridDim.x * blockDim.x;
  for (size_t i = tid; i < (size_t)SBH; i += stride) x_bf[i] = (__bf16)x[i];
  const float* Ws[4] = {Wf, Wi, Wg, Wo};
  for (size_t i = tid; i < (size_t)4 * 1024 * 2048; i += stride) {
    int g = (int)(i >> 21);
    int j = (int)((i >> 11) & 1023);
    int k = (int)(i & 2047);
    float v = Ws[g][(size_t)j * 2048 + k];
    if (k < HID) w_x[((size_t)(g * 1024 + j)) * HID + k] = (__bf16)v;
    else         w_h[((size_t)(g * 1024 + j)) * HID + (k - HID)] = (__bf16)v;
  }
  for (size_t i = tid; i < (size_t)BH; i += stride) h_buf[i] = (__bf16)h0[i];
  for (size_t i = tid; i < 256; i += stride) counters[i] = 0;
}

// 256 WGs x 256 thr (1/CU). WG: M=32 batches x N=32 cols (8 units x 4 gates).
// Wave w owns K-quarter: w0: h[0,512), w1: h[512,1024), w2: x[0,512), w3: x[512,1024).
// B (32 frags = 128 VGPRs) pinned resident via asm loads. A-h staged per step from the
// coherence point (sc0 sc1); A-x prefetched into LDS via global_load_lds off the
// critical path. z reduced across waves in LDS. out[] written during the barrier spin.
__global__ __launch_bounds__(256, 1) void lstm_kernel(
    const float* __restrict__ x, const float* __restrict__ c0,
    const float* __restrict__ bfp, const float* __restrict__ bip,
    const float* __restrict__ bgp, const float* __restrict__ bop,
    const __bf16* __restrict__ x_bf, const __bf16* __restrict__ w_x,
    const __bf16* __restrict__ w_h, __bf16* __restrict__ h_buf,
    int* __restrict__ counters, float* __restrict__ out) {
  const int tid    = threadIdx.x;
  const int wgid   = blockIdx.x;
  const int m_base = (wgid & 1) * 32;   // batch tile base: 0 or 32
  const int U      = (wgid >> 1) * 8;   // hidden-unit base (8 units per WG)
  const int wave   = tid >> 6;          // K-quarter owner
  const int lane   = tid & 63;
  const int l16    = lane & 15;
  const int kq8    = (lane >> 4) * 8;

  __shared__ __align__(16) __bf16 Ah[64 * 512];   // 64 KB: h frags  [fa=kcg*2+mt][lane*8]
  __shared__ __align__(16) __bf16 Ax[64 * 512];   // 64 KB: x frags  (same layout)
  __shared__ float zbuf[4][32][33];               // per-wave partial z tiles (padded)

  // ---- Load resident B: 32 frags (2 ntiles x 16 kc) pinned via asm volatile ----
  u32x4 Braw[32];
  {
    const __bf16* wsrc = (wave < 2) ? w_h : w_x;
    const int kbase = (wave & 1) * 512;
#pragma unroll
    for (int f = 0; f < 32; ++f) {
      int nt = f & 1, kc = f >> 1;
      int col = nt * 16 + l16;
      int wrow = (col >> 3) * 1024 + U + (col & 7);   // gate*1024 + unit
      unsigned long ga = (unsigned long)(wsrc + (size_t)wrow * HID + kbase + kc * 32 + kq8);
      asm volatile("global_load_dwordx4 %0, %1, off" : "=v"(Braw[f]) : "v"(ga));
    }
    asm volatile("s_waitcnt vmcnt(0)" ::: "memory");
  }

  // ---- Per-thread state: (b_loc = tid>>3, u_loc = tid&7) ----
  const int b_loc  = tid >> 3;
  const int u_loc  = tid & 7;
  const int j_t    = U + u_loc;
  const int b_glob = m_base + b_loc;
  float c = c0[(size_t)b_glob * HID + j_t];
  const float bias_f = bfp[j_t], bias_i = bip[j_t], bias_g = bgp[j_t], bias_o = bop[j_t];

  // ---- Prefetch x[t=0] A-frags into LDS (global_load_lds, 16 per wave) ----
#pragma unroll
  for (int i = 0; i < 16; ++i) {
    int fa = wave * 16 + i;
    int row = m_base + (fa & 1) * 16 + l16;
    int col = (fa >> 1) * 32 + kq8;
    const __bf16* g = x_bf + ((size_t)(0 * BATCH + row)) * HID + col;
    __builtin_amdgcn_global_load_lds((gas_u32p)g, (las_u32p)&Ax[fa * 512], 16, 0, 0);
  }

  for (int t = 0; t < S_LEN; ++t) {
    const size_t roff = (t & 1) ? (size_t)BH : 0;
    const size_t woff = (t & 1) ? 0 : (size_t)BH;

    // ---- (a) Stage h from coherence point into LDS (2 rounds of 8) ----
#pragma unroll
    for (int r = 0; r < 2; ++r) {
      u32x4 hv[8];
#pragma unroll
      for (int i = 0; i < 8; ++i) {
        int idx = (r * 8 + i) * 256 + tid;
        int fa = idx >> 6, s = idx & 63;
        int row = m_base + (fa & 1) * 16 + (s & 15);
        int k = (fa >> 1) * 32 + (s >> 4) * 8;
        unsigned long ga = (unsigned long)(h_buf + roff + (size_t)row * HID + k);
        asm volatile("global_load_dwordx4 %0, %1, off sc0 sc1" : "=v"(hv[i]) : "v"(ga));
      }
      asm volatile("s_waitcnt vmcnt(0)" ::: "memory");
#pragma unroll
      for (int i = 0; i < 8; ++i) {
        int idx = (r * 8 + i) * 256 + tid;
        int fa = idx >> 6, s = idx & 63;
        *(u32x4*)(&Ah[(size_t)fa * 512 + s * 8]) = hv[i];
      }
    }
    __syncthreads();   // h LDS ready; x LDS ready (prefetch drained by prior sync)

    // ---- (c) K-loop: 32 ds_read_b128 + 64 MFMA per wave, B from registers ----
    f32x4 acc00 = {0,0,0,0}, acc01 = {0,0,0,0}, acc10 = {0,0,0,0}, acc11 = {0,0,0,0};
    {
      const __bf16* Asrc = ((wave < 2) ? Ah : Ax) + (wave & 1) * 16384;
#pragma unroll
      for (int kc = 0; kc < 16; ++kc) {
        bf16x8 a0 = *(const bf16x8*)(Asrc + ((size_t)(kc * 2 + 0)) * 512 + lane * 8);
        bf16x8 a1 = *(const bf16x8*)(Asrc + ((size_t)(kc * 2 + 1)) * 512 + lane * 8);
        bf16x8 b0 = __builtin_bit_cast(bf16x8, Braw[kc * 2 + 0]);
        bf16x8 b1 = __builtin_bit_cast(bf16x8, Braw[kc * 2 + 1]);
        acc00 = __builtin_amdgcn_mfma_f32_16x16x32_bf16(a0, b0, acc00, 0, 0, 0);
        acc01 = __builtin_amdgcn_mfma_f32_16x16x32_bf16(a0, b1, acc01, 0, 0, 0);
        acc10 = __builtin_amdgcn_mfma_f32_16x16x32_bf16(a1, b0, acc10, 0, 0, 0);
        acc11 = __builtin_amdgcn_mfma_f32_16x16x32_bf16(a1, b1, acc11, 0, 0, 0);
      }
    }
    // ---- (e) z partials to LDS: C/D layout row = quad*4+r, col = l16 ----
    {
      int q = lane >> 4;
#pragma unroll
      for (int r = 0; r < 4; ++r) {
        zbuf[wave][ 0 + q * 4 + r][ 0 + l16] = acc00[r];
        zbuf[wave][ 0 + q * 4 + r][16 + l16] = acc01[r];
        zbuf[wave][16 + q * 4 + r][ 0 + l16] = acc10[r];
        zbuf[wave][16 + q * 4 + r][16 + l16] = acc11[r];
      }
    }
    __syncthreads();

    // ---- (f) Combine gates, update c, compute h, store h to coherence point ----
    float h;
    {
      float zf = 0.f, zi = 0.f, zg = 0.f, zo = 0.f;
#pragma unroll
      for (int w = 0; w < 4; ++w) {
        zf += zbuf[w][b_loc][ 0 + u_loc];
        zi += zbuf[w][b_loc][ 8 + u_loc];
        zg += zbuf[w][b_loc][16 + u_loc];
        zo += zbuf[w][b_loc][24 + u_loc];
      }
      float fg = sigm(zf + bias_f);
      float ig = sigm(zi + bias_i);
      float gg = tanh_fast(zg + bias_g);
      float og = sigm(zo + bias_o);
      c = fg * c + ig * gg;
      h = og * tanh_fast(c);
      if (t < S_LEN - 1) {
        __bf16 hb16 = (__bf16)h;
        unsigned short hbits = __builtin_bit_cast(unsigned short, hb16);
        __hip_atomic_store((unsigned short*)(h_buf + woff + (size_t)b_glob * HID + j_t),
                           hbits, __ATOMIC_RELAXED, __HIP_MEMORY_SCOPE_AGENT);
      }
    }

    // ---- (g) Prefetch x[t+1] A-frags (off critical path) ----
    if (t < S_LEN - 1) {
#pragma unroll
      for (int i = 0; i < 16; ++i) {
        int fa = wave * 16 + i;
        int row = m_base + (fa & 1) * 16 + l16;
        int col = (fa >> 1) * 32 + kq8;
        const __bf16* g = x_bf + ((size_t)((t + 1) * BATCH + row)) * HID + col;
        __builtin_amdgcn_global_load_lds((gas_u32p)g, (las_u32p)&Ax[fa * 512], 16, 0, 0);
      }
    }

    if (t < S_LEN - 1) {
      // ---- (h) barrier arrive; (i) out-writes overlap the spin ----
      __syncthreads();   // drains h stores (and prefetch issue) before arrive
      if (tid == 0)
        __hip_atomic_fetch_add(counters + t, 1, __ATOMIC_RELAXED, __HIP_MEMORY_SCOPE_AGENT);
      {
        size_t oi = ((size_t)(t * BATCH + b_glob)) * HID + j_t;
        out[oi] = x[oi] + h;
      }
      if (tid == 0) {
        while (__hip_atomic_load(counters + t, __ATOMIC_RELAXED, __HIP_MEMORY_SCOPE_AGENT) < NWG) {
          __builtin_amdgcn_s_sleep(1);
        }
      }
      __syncthreads();   // barrier exit (also drains out writes + x prefetch)
    } else {
      // last step: no barrier needed
      size_t oi = ((size_t)(t * BATCH + b_glob)) * HID + j_t;
      out[oi] = x[oi] + h;
      out[(size_t)SBH + (size_t)b_glob * HID + j_t] = h;         // h_f
      out[(size_t)SBH + BH + (size_t)b_glob * HID + j_t] = c;    // c_f
    }
  }
}

extern "C" void kernel_launch(void* const* d_in, const int* in_sizes, int n_in,
                              void* d_out, int out_size, void* d_ws, size_t ws_size,
                              hipStream_t stream) {
  const float* x   = (const float*)d_in[0];
  const float* h0  = (const float*)d_in[1];
  const float* c0  = (const float*)d_in[2];
  const float* Wf  = (const float*)d_in[3];
  const float* bf_ = (const float*)d_in[4];
  const float* Wi  = (const float*)d_in[5];
  const float* bi_ = (const float*)d_in[6];
  const float* Wg  = (const float*)d_in[7];
  const float* bg_ = (const float*)d_in[8];
  const float* Wo  = (const float*)d_in[9];
  const float* bo_ = (const float*)d_in[10];

  char* ws = (char*)d_ws;
  size_t off = 0;
  __bf16* x_bf = (__bf16*)(ws + off); off += (size_t)SBH * 2;              // 32 MB
  __bf16* w_x  = (__bf16*)(ws + off); off += (size_t)4 * 1024 * 1024 * 2;  // 8 MB
  __bf16* w_h  = (__bf16*)(ws + off); off += (size_t)4 * 1024 * 1024 * 2;  // 8 MB
  __bf16* h_buf = (__bf16*)(ws + off); off += (size_t)2 * BH * 2;          // 256 KB
  int* counters = (int*)(ws + off); off += 256 * sizeof(int);
  if (ws_size < off) return;

  float* out = (float*)d_out;

  prep_kernel<<<2048, 256, 0, stream>>>(x, h0, Wf, Wi, Wg, Wo, x_bf, w_x, w_h, h_buf, counters);
  lstm_kernel<<<NWG, 256, 0, stream>>>(x, c0, bf_, bi_, bg_, bo_, x_bf, w_x, w_h, h_buf, counters, out);
}

// Round 5
// 1415.981 us; speedup vs baseline: 1.9364x; 1.9364x over previous
//
#include <hip/hip_runtime.h>

typedef __bf16 bf16x8 __attribute__((ext_vector_type(8)));
typedef float f32x4 __attribute__((ext_vector_type(4)));
typedef unsigned int u32x4 __attribute__((ext_vector_type(4)));

#define S_LEN 256
#define BATCH 64
#define HID   1024
#define NWG   256
#define SBH   (S_LEN * BATCH * HID)   /* 16777216 */
#define BH    (BATCH * HID)           /* 65536 */

__device__ __forceinline__ float sigm(float v) { return 1.0f / (1.0f + __expf(-v)); }
__device__ __forceinline__ float tanh_fast(float v) {
  float e = __expf(-2.0f * __builtin_fabsf(v));
  float r = (1.0f - e) / (1.0f + e);
  return __builtin_copysignf(r, v);
}

// One asm block: 16 x global_load_dwordx4 from base %16 + kc*64B, then vmcnt(0).
// Early-clobber outputs + internal waitcnt => no compiler copy can read in-flight regs.
#define LOAD16_X4(dst, base, MODS)                                            \
  asm volatile(                                                               \
      "global_load_dwordx4 %0,  %16, off offset:0 " MODS "\n\t"               \
      "global_load_dwordx4 %1,  %16, off offset:64 " MODS "\n\t"              \
      "global_load_dwordx4 %2,  %16, off offset:128 " MODS "\n\t"             \
      "global_load_dwordx4 %3,  %16, off offset:192 " MODS "\n\t"             \
      "global_load_dwordx4 %4,  %16, off offset:256 " MODS "\n\t"             \
      "global_load_dwordx4 %5,  %16, off offset:320 " MODS "\n\t"             \
      "global_load_dwordx4 %6,  %16, off offset:384 " MODS "\n\t"             \
      "global_load_dwordx4 %7,  %16, off offset:448 " MODS "\n\t"             \
      "global_load_dwordx4 %8,  %16, off offset:512 " MODS "\n\t"             \
      "global_load_dwordx4 %9,  %16, off offset:576 " MODS "\n\t"             \
      "global_load_dwordx4 %10, %16, off offset:640 " MODS "\n\t"             \
      "global_load_dwordx4 %11, %16, off offset:704 " MODS "\n\t"             \
      "global_load_dwordx4 %12, %16, off offset:768 " MODS "\n\t"             \
      "global_load_dwordx4 %13, %16, off offset:832 " MODS "\n\t"             \
      "global_load_dwordx4 %14, %16, off offset:896 " MODS "\n\t"             \
      "global_load_dwordx4 %15, %16, off offset:960 " MODS "\n\t"             \
      "s_waitcnt vmcnt(0)"                                                    \
      : "=&v"((dst)[0]), "=&v"((dst)[1]), "=&v"((dst)[2]), "=&v"((dst)[3]),   \
        "=&v"((dst)[4]), "=&v"((dst)[5]), "=&v"((dst)[6]), "=&v"((dst)[7]),   \
        "=&v"((dst)[8]), "=&v"((dst)[9]), "=&v"((dst)[10]), "=&v"((dst)[11]), \
        "=&v"((dst)[12]), "=&v"((dst)[13]), "=&v"((dst)[14]), "=&v"((dst)[15])\
      : "v"(base)                                                             \
      : "memory")

// bar layout (ints): cnt[8][256] at 0, root[256] at 2048, go[8][256] at 2304. Total 4352.
__global__ void prep_kernel(const float* __restrict__ x, const float* __restrict__ h0,
                            const float* __restrict__ Wf, const float* __restrict__ Wi,
                            const float* __restrict__ Wg, const float* __restrict__ Wo,
                            __bf16* __restrict__ x_bf, __bf16* __restrict__ w_x,
                            __bf16* __restrict__ w_h, __bf16* __restrict__ h_buf,
                            int* __restrict__ bar) {
  size_t tid = (size_t)blockIdx.x * blockDim.x + threadIdx.x;
  size_t stride = (size_t)gridDim.x * blockDim.x;
  for (size_t i = tid; i < (size_t)SBH; i += stride) x_bf[i] = (__bf16)x[i];
  const float* Ws[4] = {Wf, Wi, Wg, Wo};
  for (size_t i = tid; i < (size_t)4 * 1024 * 2048; i += stride) {
    int g = (int)(i >> 21);
    int j = (int)((i >> 11) & 1023);
    int k = (int)(i & 2047);
    float v = Ws[g][(size_t)j * 2048 + k];
    if (k < HID) w_x[((size_t)(g * 1024 + j)) * HID + k] = (__bf16)v;
    else         w_h[((size_t)(g * 1024 + j)) * HID + (k - HID)] = (__bf16)v;
  }
  for (size_t i = tid; i < (size_t)BH; i += stride) h_buf[i] = (__bf16)h0[i];
  for (size_t i = tid; i < 4352; i += stride) bar[i] = 0;
}

// 256 WGs x 256 thr (1 WG/CU). WG: M=16 batches x N=64 gate-cols (16 units x 4 gates).
// Wave w owns K-quarter: w0/w1 = h k[0,512)/[512,1024) (LLC sc0sc1 loads);
// w2/w3 = x (cached loads). B: 64 frags resident (asm-pinned, may spill to AGPRs).
// A: 16 frags straight into registers per step — no LDS staging. z combined in LDS.
// Grid barrier: 8 group counters -> root -> 8 go words (parallel LLC lines).
__global__ __launch_bounds__(256, 1) void lstm_kernel(
    const float* __restrict__ x, const float* __restrict__ c0,
    const float* __restrict__ bfp, const float* __restrict__ bip,
    const float* __restrict__ bgp, const float* __restrict__ bop,
    const __bf16* __restrict__ x_bf, const __bf16* __restrict__ w_x,
    const __bf16* __restrict__ w_h, __bf16* __restrict__ h_buf,
    int* __restrict__ bar, float* __restrict__ out) {
  const int tid    = threadIdx.x;
  const int wgid   = blockIdx.x;
  const int m_base = (wgid & 3) * 16;    // batch tile: 0/16/32/48
  const int U      = (wgid >> 2) * 16;   // 16 hidden units per WG
  const int wave   = tid >> 6;           // K-quarter owner
  const int lane   = tid & 63;
  const int l16    = lane & 15;
  const int kq8    = (lane >> 4) * 8;
  const int grp    = wgid & 7;

  int* cnt  = bar;          // cnt[g*256 + t]
  int* root = bar + 2048;   // root[t]
  int* go   = bar + 2304;   // go[g*256 + t]

  __shared__ float zbuf[4][16][65];      // per-wave partial z tiles (padded stride 65)

  // ---- Resident B: 64 frags (4 gates x 16 kc), one safe asm block per gate ----
  u32x4 Braw[64];
  {
    const __bf16* wsrc = (wave < 2) ? w_h : w_x;
    const int kbase = (wave & 1) * 512;
#pragma unroll
    for (int n = 0; n < 4; ++n) {
      unsigned long gb =
          (unsigned long)(wsrc + (size_t)(n * 1024 + U + l16) * HID + kbase + kq8);
      LOAD16_X4(&Braw[n * 16], gb, "");
    }
  }

  // ---- Per-thread state: (b_loc = tid>>4, u_loc = tid&15) ----
  const int b_loc  = tid >> 4;
  const int u_loc  = tid & 15;
  const int j_t    = U + u_loc;
  const int b_glob = m_base + b_loc;
  float c = c0[(size_t)b_glob * HID + j_t];
  const float bias_f = bfp[j_t], bias_i = bip[j_t], bias_g = bgp[j_t], bias_o = bop[j_t];

  for (int t = 0; t < S_LEN; ++t) {
    const size_t roff = (t & 1) ? (size_t)BH : 0;
    const size_t woff = (t & 1) ? 0 : (size_t)BH;

    // ---- A frags straight to registers (no LDS) ----
    u32x4 Araw[16];
    if (wave < 2) {
      unsigned long ga = (unsigned long)(h_buf + roff + (size_t)(m_base + l16) * HID +
                                         (wave & 1) * 512 + kq8);
      LOAD16_X4(Araw, ga, "sc0 sc1");
    } else {
      const __bf16* xp =
          x_bf + ((size_t)(t * BATCH + m_base + l16)) * HID + (wave & 1) * 512 + kq8;
#pragma unroll
      for (int kc = 0; kc < 16; ++kc) Araw[kc] = *(const u32x4*)(xp + kc * 32);
    }

    // ---- 64 MFMAs: 4 independent gate chains ----
    f32x4 acc0 = {0,0,0,0}, acc1 = {0,0,0,0}, acc2 = {0,0,0,0}, acc3 = {0,0,0,0};
#pragma unroll
    for (int kc = 0; kc < 16; ++kc) {
      bf16x8 a = __builtin_bit_cast(bf16x8, Araw[kc]);
      acc0 = __builtin_amdgcn_mfma_f32_16x16x32_bf16(a, __builtin_bit_cast(bf16x8, Braw[ 0 + kc]), acc0, 0, 0, 0);
      acc1 = __builtin_amdgcn_mfma_f32_16x16x32_bf16(a, __builtin_bit_cast(bf16x8, Braw[16 + kc]), acc1, 0, 0, 0);
      acc2 = __builtin_amdgcn_mfma_f32_16x16x32_bf16(a, __builtin_bit_cast(bf16x8, Braw[32 + kc]), acc2, 0, 0, 0);
      acc3 = __builtin_amdgcn_mfma_f32_16x16x32_bf16(a, __builtin_bit_cast(bf16x8, Braw[48 + kc]), acc3, 0, 0, 0);
    }

    // ---- z partials to LDS: C/D row = quad*4+r (batch-local), col = gate*16 + l16 ----
    {
      int q = lane >> 4;
#pragma unroll
      for (int r = 0; r < 4; ++r) {
        zbuf[wave][q * 4 + r][ 0 + l16] = acc0[r];
        zbuf[wave][q * 4 + r][16 + l16] = acc1[r];
        zbuf[wave][q * 4 + r][32 + l16] = acc2[r];
        zbuf[wave][q * 4 + r][48 + l16] = acc3[r];
      }
    }
    __syncthreads();

    // ---- Combine gates, update c, h; store h to coherence point ----
    float h;
    {
      float zf = 0.f, zi = 0.f, zg = 0.f, zo = 0.f;
#pragma unroll
      for (int w = 0; w < 4; ++w) {
        zf += zbuf[w][b_loc][ 0 + u_loc];
        zi += zbuf[w][b_loc][16 + u_loc];
        zg += zbuf[w][b_loc][32 + u_loc];
        zo += zbuf[w][b_loc][48 + u_loc];
      }
      float fg = sigm(zf + bias_f);
      float ig = sigm(zi + bias_i);
      float gg = tanh_fast(zg + bias_g);
      float og = sigm(zo + bias_o);
      c = fg * c + ig * gg;
      h = og * tanh_fast(c);
      if (t < S_LEN - 1) {
        __bf16 hb16 = (__bf16)h;
        unsigned short hbits = __builtin_bit_cast(unsigned short, hb16);
        __hip_atomic_store((unsigned short*)(h_buf + woff + (size_t)b_glob * HID + j_t),
                           hbits, __ATOMIC_RELAXED, __HIP_MEMORY_SCOPE_AGENT);
      }
    }

    if (t < S_LEN - 1) {
      // ---- Hierarchical barrier; out-write overlaps the spin ----
      __syncthreads();   // vmcnt(0): h stores complete before arrive
      if (tid == 0) {
        int old = __hip_atomic_fetch_add(&cnt[grp * 256 + t], 1,
                                         __ATOMIC_RELAXED, __HIP_MEMORY_SCOPE_AGENT);
        if (old == 31) {
          int r = __hip_atomic_fetch_add(&root[t], 1,
                                         __ATOMIC_RELAXED, __HIP_MEMORY_SCOPE_AGENT);
          if (r == 7) {
#pragma unroll
            for (int gg = 0; gg < 8; ++gg)
              __hip_atomic_store(&go[gg * 256 + t], 1,
                                 __ATOMIC_RELAXED, __HIP_MEMORY_SCOPE_AGENT);
          }
        }
      }
      {
        size_t oi = ((size_t)(t * BATCH + b_glob)) * HID + j_t;
        out[oi] = x[oi] + h;
      }
      if (tid == 0) {
        while (__hip_atomic_load(&go[grp * 256 + t],
                                 __ATOMIC_RELAXED, __HIP_MEMORY_SCOPE_AGENT) == 0) {
          __builtin_amdgcn_s_sleep(1);
        }
      }
      __syncthreads();
    } else {
      size_t oi = ((size_t)(t * BATCH + b_glob)) * HID + j_t;
      out[oi] = x[oi] + h;
      out[(size_t)SBH + (size_t)b_glob * HID + j_t] = h;         // h_f
      out[(size_t)SBH + BH + (size_t)b_glob * HID + j_t] = c;    // c_f
    }
  }
}

extern "C" void kernel_launch(void* const* d_in, const int* in_sizes, int n_in,
                              void* d_out, int out_size, void* d_ws, size_t ws_size,
                              hipStream_t stream) {
  const float* x   = (const float*)d_in[0];
  const float* h0  = (const float*)d_in[1];
  const float* c0  = (const float*)d_in[2];
  const float* Wf  = (const float*)d_in[3];
  const float* bf_ = (const float*)d_in[4];
  const float* Wi  = (const float*)d_in[5];
  const float* bi_ = (const float*)d_in[6];
  const float* Wg  = (const float*)d_in[7];
  const float* bg_ = (const float*)d_in[8];
  const float* Wo  = (const float*)d_in[9];
  const float* bo_ = (const float*)d_in[10];

  char* ws = (char*)d_ws;
  size_t off = 0;
  __bf16* x_bf = (__bf16*)(ws + off); off += (size_t)SBH * 2;              // 32 MB
  __bf16* w_x  = (__bf16*)(ws + off); off += (size_t)4 * 1024 * 1024 * 2;  // 8 MB
  __bf16* w_h  = (__bf16*)(ws + off); off += (size_t)4 * 1024 * 1024 * 2;  // 8 MB
  __bf16* h_buf = (__bf16*)(ws + off); off += (size_t)2 * BH * 2;          // 256 KB
  int* bar = (int*)(ws + off); off += 4352 * sizeof(int);
  if (ws_size < off) return;

  float* out = (float*)d_out;

  prep_kernel<<<2048, 256, 0, stream>>>(x, h0, Wf, Wi, Wg, Wo, x_bf, w_x, w_h, h_buf, bar);
  lstm_kernel<<<NWG, 256, 0, stream>>>(x, c0, bf_, bi_, bg_, bo_, x_bf, w_x, w_h, h_buf, bar, out);
}